// Round 4
// baseline (790.189 us; speedup 1.0000x reference)
//
#include <hip/hip_runtime.h>
#include <hip/hip_fp16.h>

// Sizes fixed by the reference.
#define BB 2
#define HH 16
#define SS 2048
#define DD 128
#define NEGF (-65504.0f)   // post-softmax identical to reference NEG=-1e9

typedef __attribute__((ext_vector_type(8))) _Float16 f16x8;
typedef __attribute__((ext_vector_type(4))) float    f32x4;

// k_norm = k / max(||k||_2 over HEAD axis, eps), cast to f16.
__global__ void knorm_f16(const float* __restrict__ k, _Float16* __restrict__ kh) {
  int t = blockIdx.x * 256 + threadIdx.x;      // [0, B*S*D)
  int d = t & (DD - 1);
  int s = (t >> 7) & (SS - 1);
  int b = t >> 18;                              // S*D = 2^18
  const float* kp = k + (size_t)b * HH * SS * DD + (size_t)s * DD + d;
  float vals[HH];
  float ss = 0.f;
  #pragma unroll
  for (int h = 0; h < HH; ++h) { float x = kp[(size_t)h * SS * DD]; vals[h] = x; ss += x * x; }
  float r = 1.0f / fmaxf(sqrtf(ss), 1e-12f);
  _Float16* op = kh + (size_t)b * HH * SS * DD + (size_t)s * DD + d;
  #pragma unroll
  for (int h = 0; h < HH; ++h) op[(size_t)h * SS * DD] = (_Float16)(vals[h] * r);
}

// q -> f16, 8 elements/thread.
__global__ void cvt_f16(const float* __restrict__ x, _Float16* __restrict__ y) {
  size_t i = ((size_t)blockIdx.x * 256 + threadIdx.x) * 8;
  float4 a = *(const float4*)(x + i);
  float4 b = *(const float4*)(x + i + 4);
  f16x8 r = { (_Float16)a.x, (_Float16)a.y, (_Float16)a.z, (_Float16)a.w,
              (_Float16)b.x, (_Float16)b.y, (_Float16)b.z, (_Float16)b.w };
  *(f16x8*)(y + i) = r;
}

// v[b,h,s,d] -> vt[b,h,d,s] as f16 (PV B-operand: 8 contiguous keys at fixed d).
__global__ void vtrans_f16(const float* __restrict__ v, _Float16* __restrict__ vt) {
  __shared__ float tile[32][33];
  int bh = blockIdx.z;
  int d0 = blockIdx.x * 32, s0 = blockIdx.y * 32;
  const float* vp = v + (size_t)bh * SS * DD;
  _Float16* tp = vt + (size_t)bh * SS * DD;
  int tx = threadIdx.x, ty = threadIdx.y;       // block (32,8)
  #pragma unroll
  for (int i = ty; i < 32; i += 8)
    tile[i][tx] = vp[(size_t)(s0 + i) * DD + d0 + tx];
  __syncthreads();
  #pragma unroll
  for (int i = ty; i < 32; i += 8)
    tp[(size_t)(d0 + i) * SS + s0 + tx] = (_Float16)tile[tx][i];
}

// ---------------- Kernel A: scores + mask + softmax + attn(f32) store -------
// WG = 1024 thr (16 waves), QBLK=16. Wave w owns keys [w*128, w*128+128):
// acc[8] = 32 f32/lane. Swapped MFMA(K,Q): D[key][q], lane(lo16,g) holds
// q=lo16, keys kt*16+g*4+i. Softmax: shfl over g + 16-wide LDS reduce.
// attn written directly from regs in f32 (no LDS staging, no f16 rounding).
__global__ __launch_bounds__(1024, 4) void scores_f16(
    const _Float16* __restrict__ qh, const _Float16* __restrict__ kh,
    const int* __restrict__ mask, float* __restrict__ attn)
{
  __shared__ float redmax[16][17];   // [q][wave], padded vs bank conflicts
  __shared__ float redsum[16][17];

  // XCD swizzle: wgid%8 = XCD; each XCD owns 4 heads, walks their q-tiles.
  const int wgid = blockIdx.x;                  // [0, 4096)
  const int xcd  = wgid & 7;
  const int idx  = wgid >> 3;                   // [0, 512)
  const int bh   = (xcd << 2) | (idx >> 7);     // 4 heads per XCD
  const int q0   = (idx & 127) * 16;
  const int b    = bh >> 4;

  const int lane = threadIdx.x & 63;
  const int w    = threadIdx.x >> 6;            // [0,16)
  const int lo16 = lane & 15;
  const int g    = lane >> 4;

  const size_t hoff = (size_t)bh * SS * DD;
  const _Float16* Q = qh + hoff + (size_t)q0 * DD;
  const _Float16* K = kh + hoff;
  const int* mrow = mask + b * SS;

  // Q fragments (B operand): lane holds Q[q0+lo16][c*32+g*8 .. +7]
  f16x8 qf[4];
  #pragma unroll
  for (int c = 0; c < 4; ++c)
    qf[c] = *(const f16x8*)(Q + lo16 * DD + c * 32 + g * 8);

  // ---- scores for this wave's 128 keys ----
  f32x4 acc[8];
  #pragma unroll
  for (int kt = 0; kt < 8; ++kt) {
    const int key0 = w * 128 + kt * 16;
    f32x4 a = {0.f, 0.f, 0.f, 0.f};
    #pragma unroll
    for (int c = 0; c < 4; ++c) {
      f16x8 kf = *(const f16x8*)(K + (size_t)(key0 + lo16) * DD + c * 32 + g * 8);
      a = __builtin_amdgcn_mfma_f32_16x16x32_f16(kf, qf[c], a, 0, 0, 0);
    }
    const int4 mv = *(const int4*)(mrow + key0 + g * 4);
    a[0] = mv.x ? a[0] : NEGF;
    a[1] = mv.y ? a[1] : NEGF;
    a[2] = mv.z ? a[2] : NEGF;
    a[3] = mv.w ? a[3] : NEGF;
    acc[kt] = a;
  }

  // ---- softmax over the full row (lane's q = q0 + lo16) ----
  float m = -3.0e38f;
  #pragma unroll
  for (int kt = 0; kt < 8; ++kt)
    m = fmaxf(m, fmaxf(fmaxf(acc[kt][0], acc[kt][1]), fmaxf(acc[kt][2], acc[kt][3])));
  m = fmaxf(m, __shfl_xor(m, 16));
  m = fmaxf(m, __shfl_xor(m, 32));
  if (lane < 16) redmax[lane][w] = m;
  __syncthreads();
  float M = -3.0e38f;
  #pragma unroll
  for (int j = 0; j < 16; ++j) M = fmaxf(M, redmax[lo16][j]);

  float ssum = 0.f;
  #pragma unroll
  for (int kt = 0; kt < 8; ++kt) {
    #pragma unroll
    for (int i = 0; i < 4; ++i) {
      float p = __expf(acc[kt][i] - M);
      acc[kt][i] = p;
      ssum += p;
    }
  }
  ssum += __shfl_xor(ssum, 16);
  ssum += __shfl_xor(ssum, 32);
  if (lane < 16) redsum[lane][w] = ssum;
  __syncthreads();
  float denom = 0.f;
  #pragma unroll
  for (int j = 0; j < 16; ++j) denom += redsum[lo16][j];
  const float inv = 1.0f / denom;

  // ---- attn store, f32 straight from regs ----
  // lane stores 16 B at attn[q0+lo16][w*128 + kt*16 + g*4]; consecutive kt
  // fill adjacent 64-B half-lines -> TCC write-combines.
  float* arow = attn + ((size_t)bh * SS + q0 + lo16) * SS + w * 128;
  #pragma unroll
  for (int kt = 0; kt < 8; ++kt) {
    f32x4 p = { acc[kt][0] * inv, acc[kt][1] * inv, acc[kt][2] * inv, acc[kt][3] * inv };
    *(f32x4*)(arow + kt * 16 + g * 4) = p;
  }
}

// ---------------- Kernel B: out = attn @ v ---------------------------------
// WG = 512 thr (8 waves). Per WG: 64 q-rows x full D=128. Wave w: q-subtile
// (w&3)*16, d-half (w>>2)*64. Streams attn f32 (coalesced 128-B row
// segments), casts to f16, MFMA with vth[d][s]. No LDS.
__global__ __launch_bounds__(512, 4) void pv_f16(
    const float* __restrict__ attn, const _Float16* __restrict__ vth,
    float* __restrict__ out)
{
  const int wgid = blockIdx.x;                  // [0, 1024)
  const int xcd  = wgid & 7;
  const int idx  = wgid >> 3;                   // [0, 128)
  const int bh   = (xcd << 2) | (idx >> 5);     // same head->XCD map as A
  const int q0   = (idx & 31) * 64;

  const int lane = threadIdx.x & 63;
  const int w    = threadIdx.x >> 6;            // [0,8)
  const int qs   = (w & 3) * 16;
  const int dh   = (w >> 2) * 64;
  const int lo16 = lane & 15;
  const int g    = lane >> 4;

  const size_t hoff = (size_t)bh * SS * DD;
  const float* A = attn + ((size_t)bh * SS + q0 + qs + lo16) * SS + g * 8;
  const _Float16* V = vth + hoff + (size_t)(dh + lo16) * SS + g * 8;

  f32x4 oacc[4] = { {0,0,0,0}, {0,0,0,0}, {0,0,0,0}, {0,0,0,0} };

  #pragma unroll 4
  for (int kt = 0; kt < 64; ++kt) {
    const int k0 = kt * 32;
    // A-fragment: P[q][k0+g*8 .. +7] from f32 attn, cvt to f16
    f32x4 a0 = *(const f32x4*)(A + k0);
    f32x4 a1 = *(const f32x4*)(A + k0 + 4);
    f16x8 pf = { (_Float16)a0[0], (_Float16)a0[1], (_Float16)a0[2], (_Float16)a0[3],
                 (_Float16)a1[0], (_Float16)a1[1], (_Float16)a1[2], (_Float16)a1[3] };
    #pragma unroll
    for (int t = 0; t < 4; ++t) {
      f16x8 vf = *(const f16x8*)(V + (size_t)(t * 16) * SS + k0);
      oacc[t] = __builtin_amdgcn_mfma_f32_16x16x32_f16(pf, vf, oacc[t], 0, 0, 0);
    }
  }

  float* O = out + hoff + (size_t)(q0 + qs) * DD + dh;
  #pragma unroll
  for (int t = 0; t < 4; ++t) {
    #pragma unroll
    for (int i = 0; i < 4; ++i) {
      const int qrow = g * 4 + i;               // C row = q, col = d
      O[(size_t)qrow * DD + t * 16 + lo16] = oacc[t][i];
    }
  }
}

extern "C" void kernel_launch(void* const* d_in, const int* in_sizes, int n_in,
                              void* d_out, int out_size, void* d_ws, size_t ws_size,
                              hipStream_t stream) {
  const float* q    = (const float*)d_in[0];
  const float* k    = (const float*)d_in[1];
  const float* v    = (const float*)d_in[2];
  const int*   mask = (const int*)d_in[3];

  const size_t N = (size_t)BB * HH * SS * DD;     // 8388608
  float* out  = (float*)d_out;
  float* attn = out + N;                          // outputs concatenated (out, attn)

  // scratch: 3 f16 tensors = 48 MB
  _Float16* qh  = (_Float16*)d_ws;
  _Float16* kh  = qh + N;
  _Float16* vth = kh + N;

  cvt_f16  <<<N / 8 / 256, 256, 0, stream>>>(q, qh);
  knorm_f16<<<(BB * SS * DD) / 256, 256, 0, stream>>>(k, kh);
  vtrans_f16<<<dim3(DD / 32, SS / 32, BB * HH), dim3(32, 8), 0, stream>>>(v, vth);

  scores_f16<<<4096, 1024, 0, stream>>>(qh, kh, mask, attn);
  pv_f16    <<<1024,  512, 0, stream>>>(attn, vth, out);
}